// Round 9
// baseline (1016.524 us; speedup 1.0000x reference)
//
#include <hip/hip_runtime.h>

// GCN 2-layer on MI355X — Round 19: atomic-tax removal. Measured constant
// from R15/R17/R18: LDS atomic RMW ~4.2cy per active lane, serialized,
// independent of int/float, conflicts, batching -> every 6.4M-lane-op
// kernel costs ~43us. The old pipeline had 25.6M LDS-atomic lane-ops
// (countA+scatterA+localC). New pipeline: NO LDS atomics, NO partition
// sort — build a full CSR directly with GLOBAL int atomics (parallelize
// across L2 slices; hist dirties only deg-array lines):
//   zero -> histd (global atomicAdd deg) -> dinvg -> scanL/scanS/scanAdd
//   (rowStart, cur) -> scatter (pos=atomicAdd(cur[dst]); srcsorted[pos])
//   -> agg1/agg2: block = 64 nodes = ONE contiguous span (~2048 edges):
//      phase1 stage gathers to LDS (4 in flight/thread, 1 barrier pair),
//      phase2 thread-per-(node,comp) LDS sums, fused epilogue.
//
// g[j] = x[j]*dinv[j].  layer1: hs2 via relu(dinv*(sum g)+b1)@W2*dinv
// layer2: out[i] = dinv[i]*(sum hs2[src]+hs2[i]) + b2
//
// ws: deg[nd]|rowStart[nd+4]|cur[nd]|srcsorted[E]|blockTotal[128]|
//     dinv[nd]|g[2nd]|hs2[4nd]   ~33 MB

#define LPBIT 11     // scan-block size bits (2048 deg entries per block)
#define NB    64     // nodes per aggregation block
#define CAP   2432   // staged edges per block (mean 2048, sigma~45)

// ---------------- degree histogram (global atomics) ----------------

__global__ __launch_bounds__(512) void zero_kernel(int* __restrict__ deg, int nd) {
    int i = blockIdx.x * 512 + threadIdx.x;
    if (i < nd) deg[i] = 0;
}

__global__ __launch_bounds__(512) void histd_kernel(
    const int* __restrict__ dst, int* __restrict__ deg, int E) {
    int nv4 = E >> 2;
    const int4* d4 = (const int4*)dst;
    for (int i = blockIdx.x * 512 + threadIdx.x; i < nv4; i += gridDim.x * 512) {
        int4 d = d4[i];
        atomicAdd(&deg[d.x], 1);
        atomicAdd(&deg[d.y], 1);
        atomicAdd(&deg[d.z], 1);
        atomicAdd(&deg[d.w], 1);
    }
    if (blockIdx.x == 0) {  // scalar tail (E % 4)
        int e = (nv4 << 2) + threadIdx.x;
        if (e < E) atomicAdd(&deg[dst[e]], 1);
    }
}

__global__ __launch_bounds__(512) void dinvg_kernel(
    const int* __restrict__ deg, const float* __restrict__ x,
    float* __restrict__ dinv, float* __restrict__ g, int n) {
    int i = blockIdx.x * 512 + threadIdx.x;
    if (i >= n) return;
    float d = rsqrtf((float)deg[i] + 1.0f);  // +1 self-loop
    dinv[i] = d;
    float2 xv = ((const float2*)x)[i];
    ((float2*)g)[i] = make_float2(xv.x * d, xv.y * d);
}

// ---------------- rowStart = exclusive scan of deg ----------------

__global__ __launch_bounds__(512) void scanL_kernel(
    const int* __restrict__ deg, int* __restrict__ rowStart,
    int* __restrict__ blockTotal) {
    __shared__ int sdata[512];
    int tid = threadIdx.x;
    int base = blockIdx.x << LPBIT;
    int v[4];
    int s = 0;
    #pragma unroll
    for (int k = 0; k < 4; k++) {
        v[k] = deg[base + tid * 4 + k];
        s += v[k];
    }
    int x = s;
    sdata[tid] = x;
    __syncthreads();
    for (int off = 1; off < 512; off <<= 1) {
        int t = (tid >= off) ? sdata[tid - off] : 0;
        __syncthreads();
        x += t;
        sdata[tid] = x;
        __syncthreads();
    }
    int run = x - s;
    #pragma unroll
    for (int k = 0; k < 4; k++) {
        rowStart[base + tid * 4 + k] = run;
        run += v[k];
    }
    if (tid == 511) blockTotal[blockIdx.x] = x;
}

__global__ __launch_bounds__(128) void scanS_kernel(
    int* __restrict__ blockTotal, int P) {
    __shared__ int sdata[128];
    int tid = threadIdx.x;
    int v = (tid < P) ? blockTotal[tid] : 0;
    int x = v;
    sdata[tid] = x;
    __syncthreads();
    for (int off = 1; off < 128; off <<= 1) {
        int t = (tid >= off) ? sdata[tid - off] : 0;
        __syncthreads();
        x += t;
        sdata[tid] = x;
        __syncthreads();
    }
    if (tid < P) blockTotal[tid] = x - v;  // exclusive
}

__global__ __launch_bounds__(512) void scanAdd_kernel(
    int* __restrict__ rowStart, int* __restrict__ cur,
    const int* __restrict__ blockOff, int nd, int E) {
    int i = blockIdx.x * 512 + threadIdx.x;
    if (i == 0) rowStart[nd] = E;
    if (i < nd) {
        int r = rowStart[i] + blockOff[i >> LPBIT];
        rowStart[i] = r;
        cur[i] = r;
    }
}

// ---------------- direct CSR scatter (global atomic-rtn) ----------------

__global__ __launch_bounds__(512) void scatter_kernel(
    const int* __restrict__ src, const int* __restrict__ dst,
    int* __restrict__ cur, int* __restrict__ srcsorted, int E) {
    int nv4 = E >> 2;
    const int4* d4 = (const int4*)dst;
    const int4* s4 = (const int4*)src;
    for (int i = blockIdx.x * 512 + threadIdx.x; i < nv4; i += gridDim.x * 512) {
        int4 d = d4[i];
        int4 sv = s4[i];
        int p0 = atomicAdd(&cur[d.x], 1);
        int p1 = atomicAdd(&cur[d.y], 1);
        int p2 = atomicAdd(&cur[d.z], 1);
        int p3 = atomicAdd(&cur[d.w], 1);
        srcsorted[p0] = sv.x;
        srcsorted[p1] = sv.y;
        srcsorted[p2] = sv.z;
        srcsorted[p3] = sv.w;
    }
    if (blockIdx.x == 0) {  // scalar tail
        int e = (nv4 << 2) + threadIdx.x;
        if (e < E) {
            int pos = atomicAdd(&cur[dst[e]], 1);
            srcsorted[pos] = src[e];
        }
    }
}

// ---------------- two-phase aggregation, one span per block -------------

__global__ __launch_bounds__(512) void agg1_kernel(
    const int* __restrict__ srcsorted, const int* __restrict__ rowStart,
    const float* __restrict__ g, const float* __restrict__ dinv,
    const float* __restrict__ W1, const float* __restrict__ b1,
    const float* __restrict__ W2, float* __restrict__ hs2, int n) {
    __shared__ float2 stage[CAP];
    __shared__ int rs[NB + 1];
    __shared__ float sres[NB][2];
    int tid = threadIdx.x;
    int i0 = blockIdx.x * NB;
    if (tid <= NB) rs[tid] = rowStart[i0 + tid];
    __syncthreads();
    int lo = rs[0], hi = rs[NB];
    const float2* gp = (const float2*)g;
    for (int e0 = lo + tid; e0 < hi; e0 += 2048) {
        int idx[4];
        #pragma unroll
        for (int k = 0; k < 4; k++) {
            int e = e0 + k * 512;
            idx[k] = (e < hi) ? srcsorted[e] : -1;
        }
        float2 v[4];
        #pragma unroll
        for (int k = 0; k < 4; k++)
            v[k] = (idx[k] >= 0) ? gp[idx[k]] : make_float2(0.0f, 0.0f);
        #pragma unroll
        for (int k = 0; k < 4; k++) {
            int e = e0 + k * 512;
            int off = e - lo;
            if (e < hi && off < CAP) stage[off] = v[k];
        }
    }
    __syncthreads();
    if (tid < NB * 2) {
        int nid = tid >> 1, c = tid & 1;
        int a = rs[nid] - lo, bnd = rs[nid + 1] - lo;
        float acc = 0.0f;
        for (int j = a; j < bnd; j++) {
            if (j < CAP) acc += ((float*)stage)[j * 2 + c];
            else {  // overflow fallback (P ~ 0)
                int s2 = srcsorted[lo + j];
                acc += g[2 * (size_t)s2 + c];
            }
        }
        sres[nid][c] = acc;
    }
    __syncthreads();
    if (tid < NB) {
        int i = i0 + tid;
        if (i < n) {
            float d = dinv[i];
            float2 gi = gp[i];
            float s0 = (sres[tid][0] + gi.x) * d;
            float s1 = (sres[tid][1] + gi.y) * d;
            float oc0 = 0.0f, oc1 = 0.0f, oc2 = 0.0f, oc3 = 0.0f;
            #pragma unroll
            for (int f = 0; f < 8; f++) {
                float h = fmaxf(s0 * W1[f] + s1 * W1[8 + f] + b1[f], 0.0f);
                oc0 += h * W2[4 * f];
                oc1 += h * W2[4 * f + 1];
                oc2 += h * W2[4 * f + 2];
                oc3 += h * W2[4 * f + 3];
            }
            float4 o;
            o.x = oc0 * d; o.y = oc1 * d; o.z = oc2 * d; o.w = oc3 * d;
            ((float4*)hs2)[i] = o;
        }
    }
}

__global__ __launch_bounds__(512) void agg2_kernel(
    const int* __restrict__ srcsorted, const int* __restrict__ rowStart,
    const float* __restrict__ hs2, const float* __restrict__ dinv,
    const float* __restrict__ b2, float* __restrict__ out, int n) {
    __shared__ float4 stage[CAP];
    __shared__ int rs[NB + 1];
    int tid = threadIdx.x;
    int i0 = blockIdx.x * NB;
    if (tid <= NB) rs[tid] = rowStart[i0 + tid];
    __syncthreads();
    int lo = rs[0], hi = rs[NB];
    const float4* hp = (const float4*)hs2;
    for (int e0 = lo + tid; e0 < hi; e0 += 2048) {
        int idx[4];
        #pragma unroll
        for (int k = 0; k < 4; k++) {
            int e = e0 + k * 512;
            idx[k] = (e < hi) ? srcsorted[e] : -1;
        }
        float4 v[4];
        #pragma unroll
        for (int k = 0; k < 4; k++)
            v[k] = (idx[k] >= 0) ? hp[idx[k]]
                                 : make_float4(0.0f, 0.0f, 0.0f, 0.0f);
        #pragma unroll
        for (int k = 0; k < 4; k++) {
            int e = e0 + k * 512;
            int off = e - lo;
            if (e < hi && off < CAP) stage[off] = v[k];
        }
    }
    __syncthreads();
    if (tid < NB * 4) {
        int nid = tid >> 2, c = tid & 3;
        int a = rs[nid] - lo, bnd = rs[nid + 1] - lo;
        float acc = 0.0f;
        for (int j = a; j < bnd; j++) {
            if (j < CAP) acc += ((float*)stage)[j * 4 + c];
            else {  // overflow fallback
                int s2 = srcsorted[lo + j];
                acc += hs2[4 * (size_t)s2 + c];
            }
        }
        int i = i0 + nid;
        if (i < n) {
            float d = dinv[i];
            float hv = hs2[4 * (size_t)i + c];
            out[4 * (size_t)i + c] = d * (acc + hv) + b2[c];
        }
    }
}

extern "C" void kernel_launch(void* const* d_in, const int* in_sizes, int n_in,
                              void* d_out, int out_size, void* d_ws, size_t ws_size,
                              hipStream_t stream) {
    const float* x   = (const float*)d_in[0];
    const int*   ei  = (const int*)d_in[1];
    const float* W1  = (const float*)d_in[2];
    const float* b1  = (const float*)d_in[3];
    const float* W2  = (const float*)d_in[4];
    const float* b2  = (const float*)d_in[5];
    float* out = (float*)d_out;

    const int n = in_sizes[0] / 2;  // x is [N,2]
    const int E = in_sizes[1] / 2;  // edge_index is [2,E]
    const int* src = ei;
    const int* dst = ei + E;

    const int P  = (n + (1 << LPBIT) - 1) >> LPBIT;  // scan blocks (98)
    const int nd = P << LPBIT;                       // padded node count

    int* ws = (int*)d_ws;
    int* deg       = ws;                     // nd
    int* rowStart  = deg + nd;               // nd+1 (pad 4)
    int* cur       = rowStart + nd + 4;      // nd
    int* srcsorted = cur + nd;               // E
    int* blockTotal= srcsorted + E;          // 128
    float* dinv = (float*)(blockTotal + 128);// nd
    float* g    = dinv + nd;                 // 2*nd
    float* hs2  = g + 2 * nd;                // 4*nd

    const int gNd = (nd + 511) / 512;
    const int gN  = (n + 511) / 512;
    const int gE  = 1568;                    // grid-stride for edge passes
    const int gB  = nd / NB;                 // aggregation blocks

    zero_kernel   <<<gNd, 512, 0, stream>>>(deg, nd);
    histd_kernel  <<<gE, 512, 0, stream>>>(dst, deg, E);
    dinvg_kernel  <<<gN, 512, 0, stream>>>(deg, x, dinv, g, n);
    scanL_kernel  <<<P, 512, 0, stream>>>(deg, rowStart, blockTotal);
    scanS_kernel  <<<1, 128, 0, stream>>>(blockTotal, P);
    scanAdd_kernel<<<gNd, 512, 0, stream>>>(rowStart, cur, blockTotal, nd, E);
    scatter_kernel<<<gE, 512, 0, stream>>>(src, dst, cur, srcsorted, E);
    agg1_kernel   <<<gB, 512, 0, stream>>>(srcsorted, rowStart, g, dinv, W1, b1, W2, hs2, n);
    agg2_kernel   <<<gB, 512, 0, stream>>>(srcsorted, rowStart, hs2, dinv, b2, out, n);
}

// Round 10
// 244.550 us; speedup vs baseline: 4.1567x; 4.1567x over previous
//
#include <hip/hip_runtime.h>

// GCN 2-layer on MI355X — Round 20: R14's proven sort pipeline (245us
// total, all components verified) + restructured aggregation. R14's agg
// ran 391 blocks (1.5/CU) each with 8 barrier-separated phases -> phases
// couldn't overlap (49.5us with nothing busy). New: one (bucket,
// node-slice) PARTIAL per block — agg1 3136 / agg2 6272 blocks, each a
// single stage(gather->LDS)+barrier+sum cycle; partials combined by tiny
// per-node kernels with the fused epilogues. 4 blocks/CU resident, 12-24
// per CU total -> cross-block phase overlap. No atomics/shuffles in agg.
// Partials time-overlay the dead packed[] region (no ws growth).
//
// Measured constants driving this design (R12-R19):
//  - LDS atomic RMW ~4.2cy/lane serialized (any lowering) -> 6.4M ops=43us
//  - scattered 4B global stores dirty full 64B lines (16x write amp)
//  - segmented shfl-scan ~0.5 dependent bpermute/edge -> LDS-pipe bound
//
// g[j] = x[j]*dinv[j].  layer1: hs2 via relu(dinv*(sum g)+b1)@W2*dinv
// layer2: out[i] = dinv[i]*(sum hs2[src]+hs2[i]) + b2

#define EPB   8192   // edges per pass-A block
#define PART  2048   // nodes per partition
#define LPBIT 11
#define SRCB  18     // src bits in packed
#define BC    4      // localC sub-blocks per dp
#define RSTR  2049   // runStart stride per (dp,b)
#define STCAP 17408  // LDS stage words (68 KB); max expected ~16.6k
#define NSL1  256    // nodes per agg1 slice (8 slices per (dp,b))
#define CAP1  2304   // agg1 staged edges (mean 2048, sigma~45)
#define NSL2  128    // nodes per agg2 slice (16 slices per (dp,b))
#define CAP2  1280   // agg2 staged edges (mean 1024, sigma~32)

// ---------------- Pass A ----------------

__global__ __launch_bounds__(512) void countA_kernel(
    const int* __restrict__ dst, int* __restrict__ cntmat, int E, int P) {
    __shared__ int cnt[128];
    int tid = threadIdx.x;
    if (tid < 128) cnt[tid] = 0;
    __syncthreads();
    int nv4 = E >> 2;
    int b4 = (blockIdx.x * EPB) >> 2;
    int e4 = min(b4 + (EPB >> 2), nv4);
    const int4* d4 = (const int4*)dst;
    #pragma unroll
    for (int k = 0; k < (EPB >> 2); k += 512) {
        int i = b4 + k + tid;
        if (i < e4) {
            int4 d = d4[i];
            atomicAdd(&cnt[d.x >> LPBIT], 1);
            atomicAdd(&cnt[d.y >> LPBIT], 1);
            atomicAdd(&cnt[d.z >> LPBIT], 1);
            atomicAdd(&cnt[d.w >> LPBIT], 1);
        }
    }
    if (blockIdx.x == gridDim.x - 1) {  // scalar tail (E % 4)
        int e = (nv4 << 2) + tid;
        if (e < E) atomicAdd(&cnt[dst[e] >> LPBIT], 1);
    }
    __syncthreads();
    int* row = cntmat + (size_t)blockIdx.x * P;
    if (tid < P) row[tid] = cnt[tid];
}

__global__ __launch_bounds__(256) void colscanA_kernel(
    int* __restrict__ cntmat, int* __restrict__ colTotal, int B, int P) {
    __shared__ int sdata[256];
    int p = blockIdx.x, tid = threadIdx.x;
    int v[4];
    int s = 0;
    #pragma unroll
    for (int k = 0; k < 4; k++) {
        int b = tid * 4 + k;
        v[k] = (b < B) ? cntmat[(size_t)b * P + p] : 0;
        s += v[k];
    }
    int x = s;
    sdata[tid] = x;
    __syncthreads();
    for (int off = 1; off < 256; off <<= 1) {
        int t = (tid >= off) ? sdata[tid - off] : 0;
        __syncthreads();
        x += t;
        sdata[tid] = x;
        __syncthreads();
    }
    int run = x - s;
    #pragma unroll
    for (int k = 0; k < 4; k++) {
        int b = tid * 4 + k;
        if (b < B) cntmat[(size_t)b * P + p] = run;
        run += v[k];
    }
    if (tid == 255) colTotal[p] = x;
}

__global__ __launch_bounds__(256) void totalscanA_kernel(
    const int* __restrict__ colTotal, int* __restrict__ colStart,
    int P, int E) {
    __shared__ int sdata[256];
    int tid = threadIdx.x;
    int v[4];
    int s = 0;
    #pragma unroll
    for (int k = 0; k < 4; k++) {
        int i = tid * 4 + k;
        v[k] = (i < P) ? colTotal[i] : 0;
        s += v[k];
    }
    int x = s;
    sdata[tid] = x;
    __syncthreads();
    for (int off = 1; off < 256; off <<= 1) {
        int t = (tid >= off) ? sdata[tid - off] : 0;
        __syncthreads();
        x += t;
        sdata[tid] = x;
        __syncthreads();
    }
    int run = x - s;
    #pragma unroll
    for (int k = 0; k < 4; k++) {
        int i = tid * 4 + k;
        if (i < P) colStart[i] = run;
        run += v[k];
    }
    if (tid == 0) colStart[P] = E;
}

__global__ __launch_bounds__(512) void scatterA_kernel(
    const int* __restrict__ src, const int* __restrict__ dst,
    const int* __restrict__ cntmat, const int* __restrict__ colStart,
    unsigned* __restrict__ packed, int E, int P) {
    __shared__ int cur[128];
    int tid = threadIdx.x;
    if (tid < P) cur[tid] = colStart[tid] + cntmat[(size_t)blockIdx.x * P + tid];
    __syncthreads();
    int nv4 = E >> 2;
    int b4 = (blockIdx.x * EPB) >> 2;
    int e4 = min(b4 + (EPB >> 2), nv4);
    const int4* d4 = (const int4*)dst;
    const int4* s4 = (const int4*)src;
    #pragma unroll
    for (int k = 0; k < (EPB >> 2); k += 512) {
        int i = b4 + k + tid;
        if (i < e4) {
            int4 d = d4[i];
            int4 sv = s4[i];
            int p0 = atomicAdd(&cur[d.x >> LPBIT], 1);
            packed[p0] = ((unsigned)(d.x & (PART - 1)) << SRCB) | (unsigned)sv.x;
            int p1 = atomicAdd(&cur[d.y >> LPBIT], 1);
            packed[p1] = ((unsigned)(d.y & (PART - 1)) << SRCB) | (unsigned)sv.y;
            int p2 = atomicAdd(&cur[d.z >> LPBIT], 1);
            packed[p2] = ((unsigned)(d.z & (PART - 1)) << SRCB) | (unsigned)sv.z;
            int p3 = atomicAdd(&cur[d.w >> LPBIT], 1);
            packed[p3] = ((unsigned)(d.w & (PART - 1)) << SRCB) | (unsigned)sv.w;
        }
    }
    if (blockIdx.x == gridDim.x - 1) {  // scalar tail
        int e = (nv4 << 2) + tid;
        if (e < E) {
            int d = dst[e];
            int pos = atomicAdd(&cur[d >> LPBIT], 1);
            packed[pos] = ((unsigned)(d & (PART - 1)) << SRCB) | (unsigned)src[e];
        }
    }
}

// ---------------- localC: in-place LDS counting sort per 16k range --------

__global__ __launch_bounds__(512) void localC_kernel(
    const unsigned* __restrict__ packed, const int* __restrict__ colStart,
    int* __restrict__ runStart, int* __restrict__ srcsorted) {
    __shared__ int hist[PART];      // counts -> absolute cursors
    __shared__ int sdata[512];
    __shared__ unsigned stage[STCAP];
    int tid = threadIdx.x;
    int dp = blockIdx.x >> 2, b = blockIdx.x & (BC - 1);
    int s0 = colStart[dp], len = colStart[dp + 1] - s0;
    int lo = s0 + (int)(((long long)len * b) / BC);
    int hi = s0 + (int)(((long long)len * (b + 1)) / BC);
    for (int k = tid; k < PART; k += 512) hist[k] = 0;
    __syncthreads();
    for (int i = lo + tid; i < hi; i += 512)
        atomicAdd(&hist[packed[i] >> SRCB], 1);
    __syncthreads();
    // exclusive scan of hist[2048], 4 elems/thread
    int off = tid * 4;
    int v0 = hist[off], v1 = hist[off + 1], v2 = hist[off + 2], v3 = hist[off + 3];
    int s = v0 + v1 + v2 + v3;
    int x = s;
    sdata[tid] = x;
    __syncthreads();
    for (int o = 1; o < 512; o <<= 1) {
        int t = (tid >= o) ? sdata[tid - o] : 0;
        __syncthreads();
        x += t;
        sdata[tid] = x;
        __syncthreads();
    }
    int run = x - s;  // exclusive prefix of this thread's 4 buckets
    int* rs = runStart + (size_t)(dp * BC + b) * RSTR;
    int c0 = lo + run, c1 = c0 + v0, c2 = c1 + v1, c3 = c2 + v2;
    rs[off] = c0; rs[off + 1] = c1; rs[off + 2] = c2; rs[off + 3] = c3;
    __syncthreads();  // all v-reads done before cursor overwrite
    hist[off] = c0; hist[off + 1] = c1; hist[off + 2] = c2; hist[off + 3] = c3;
    if (tid == 0) rs[PART] = hi;  // end sentinel
    __syncthreads();
    // place into LDS stage (absolute pos - lo), then coalesced flush
    int total = hi - lo;
    bool ovf = total > STCAP;
    for (int i = lo + tid; i < hi; i += 512) {
        unsigned w = packed[i];
        int pos = atomicAdd(&hist[w >> SRCB], 1);
        unsigned sv = w & ((1u << SRCB) - 1);
        if (!ovf) stage[pos - lo] = sv;
        else srcsorted[pos] = (int)sv;
    }
    __syncthreads();
    if (!ovf)
        for (int j = tid; j < total; j += 512) srcsorted[lo + j] = (int)stage[j];
}

// ---------------- Node-side ----------------

__global__ __launch_bounds__(512) void dinvg_kernel(
    const int* __restrict__ runStart, const float* __restrict__ x,
    float* __restrict__ dinv, float* __restrict__ g, int n) {
    int i = blockIdx.x * 512 + threadIdx.x;
    if (i >= n) return;
    int dp = i >> LPBIT, ld = i & (PART - 1);
    int deg = 0;
    #pragma unroll
    for (int b = 0; b < BC; b++) {
        const int* rs = runStart + (size_t)(dp * BC + b) * RSTR + ld;
        deg += rs[1] - rs[0];
    }
    float d = rsqrtf((float)deg + 1.0f);  // +1 self-loop
    dinv[i] = d;
    float2 xv = ((const float2*)x)[i];
    ((float2*)g)[i] = make_float2(xv.x * d, xv.y * d);
}

// ---------------- Partial-per-(bucket,slice) aggregation ----------------
// One stage+sum cycle per block; partial sums combined per node afterward.

__global__ __launch_bounds__(512) void agg1p_kernel(
    const int* __restrict__ srcsorted, const int* __restrict__ runStart,
    const float* __restrict__ g, float* __restrict__ partial1) {
    __shared__ float2 stage[CAP1];
    __shared__ int srs[NSL1 + 1];
    int tid = threadIdx.x;
    int bid = blockIdx.x;
    int sl = bid & 7, rb = bid >> 3;       // rb = dp*BC + b
    const int* rs = runStart + (size_t)rb * RSTR + sl * NSL1;
    if (tid <= NSL1) srs[tid] = rs[tid];
    __syncthreads();
    int lo = srs[0], hi = srs[NSL1];
    const float2* gp = (const float2*)g;
    bool ovf = (hi - lo) > CAP1;           // expected never (+5.6 sigma)
    if (!ovf)
        for (int e = lo + tid; e < hi; e += 512)
            stage[e - lo] = gp[srcsorted[e]];
    __syncthreads();
    int nid = tid >> 1, c = tid & 1;       // 256 nodes x 2 comps
    int a = srs[nid] - lo, bnd = srs[nid + 1] - lo;
    float acc = 0.0f;
    if (!ovf) {
        const float* st = (const float*)stage;
        for (int j = a; j < bnd; j++) acc += st[j * 2 + c];
    } else {
        for (int j = a; j < bnd; j++)
            acc += g[2 * (size_t)srcsorted[lo + j] + c];
    }
    partial1[(size_t)bid * 512 + tid] = acc;   // [bid][nid*2+c], coalesced
}

__global__ __launch_bounds__(512) void combine1_kernel(
    const float* __restrict__ partial1, const float* __restrict__ g,
    const float* __restrict__ dinv, const float* __restrict__ W1,
    const float* __restrict__ b1, const float* __restrict__ W2,
    float* __restrict__ hs2, int n) {
    int i = blockIdx.x * 512 + threadIdx.x;
    if (i >= n) return;
    int dp = i >> LPBIT, ld = i & (PART - 1);
    int sl = ld >> 8, off = ld & (NSL1 - 1);
    float s0 = 0.0f, s1 = 0.0f;
    #pragma unroll
    for (int b = 0; b < BC; b++) {
        int bid = ((dp * BC + b) << 3) | sl;
        const float* q = partial1 + (size_t)bid * 512 + off * 2;
        s0 += q[0];
        s1 += q[1];
    }
    float d = dinv[i];
    float2 gi = ((const float2*)g)[i];
    s0 = (s0 + gi.x) * d;
    s1 = (s1 + gi.y) * d;
    float oc0 = 0.0f, oc1 = 0.0f, oc2 = 0.0f, oc3 = 0.0f;
    #pragma unroll
    for (int f = 0; f < 8; f++) {
        float h = fmaxf(s0 * W1[f] + s1 * W1[8 + f] + b1[f], 0.0f);
        oc0 += h * W2[4 * f];
        oc1 += h * W2[4 * f + 1];
        oc2 += h * W2[4 * f + 2];
        oc3 += h * W2[4 * f + 3];
    }
    float4 o;
    o.x = oc0 * d; o.y = oc1 * d; o.z = oc2 * d; o.w = oc3 * d;
    ((float4*)hs2)[i] = o;
}

__global__ __launch_bounds__(512) void agg2p_kernel(
    const int* __restrict__ srcsorted, const int* __restrict__ runStart,
    const float* __restrict__ hs2, float* __restrict__ partial2) {
    __shared__ float4 stage[CAP2];
    __shared__ int srs[NSL2 + 1];
    int tid = threadIdx.x;
    int bid = blockIdx.x;
    int sl = bid & 15, rb = bid >> 4;      // rb = dp*BC + b
    const int* rs = runStart + (size_t)rb * RSTR + sl * NSL2;
    if (tid <= NSL2) srs[tid] = rs[tid];
    __syncthreads();
    int lo = srs[0], hi = srs[NSL2];
    const float4* hp = (const float4*)hs2;
    bool ovf = (hi - lo) > CAP2;           // expected never (+8 sigma)
    if (!ovf)
        for (int e = lo + tid; e < hi; e += 512)
            stage[e - lo] = hp[srcsorted[e]];
    __syncthreads();
    int nid = tid >> 2, c = tid & 3;       // 128 nodes x 4 comps
    int a = srs[nid] - lo, bnd = srs[nid + 1] - lo;
    float acc = 0.0f;
    if (!ovf) {
        const float* st = (const float*)stage;
        for (int j = a; j < bnd; j++) acc += st[j * 4 + c];
    } else {
        for (int j = a; j < bnd; j++)
            acc += hs2[4 * (size_t)srcsorted[lo + j] + c];
    }
    partial2[(size_t)bid * 512 + tid] = acc;   // [bid][nid*4+c], coalesced
}

__global__ __launch_bounds__(512) void combine2_kernel(
    const float* __restrict__ partial2, const float* __restrict__ hs2,
    const float* __restrict__ dinv, const float* __restrict__ b2,
    float* __restrict__ out, int n) {
    int i = blockIdx.x * 512 + threadIdx.x;
    if (i >= n) return;
    int dp = i >> LPBIT, ld = i & (PART - 1);
    int sl = ld >> 7, off = ld & (NSL2 - 1);
    float s0 = 0.0f, s1 = 0.0f, s2 = 0.0f, s3 = 0.0f;
    #pragma unroll
    for (int b = 0; b < BC; b++) {
        int bid = ((dp * BC + b) << 4) | sl;
        const float* q = partial2 + (size_t)bid * 512 + off * 4;
        s0 += q[0];
        s1 += q[1];
        s2 += q[2];
        s3 += q[3];
    }
    float d = dinv[i];
    float4 hv = ((const float4*)hs2)[i];
    float4 o;
    o.x = d * (s0 + hv.x) + b2[0];
    o.y = d * (s1 + hv.y) + b2[1];
    o.z = d * (s2 + hv.z) + b2[2];
    o.w = d * (s3 + hv.w) + b2[3];
    ((float4*)out)[i] = o;
}

extern "C" void kernel_launch(void* const* d_in, const int* in_sizes, int n_in,
                              void* d_out, int out_size, void* d_ws, size_t ws_size,
                              hipStream_t stream) {
    const float* x   = (const float*)d_in[0];
    const int*   ei  = (const int*)d_in[1];
    const float* W1  = (const float*)d_in[2];
    const float* b1  = (const float*)d_in[3];
    const float* W2  = (const float*)d_in[4];
    const float* b2  = (const float*)d_in[5];
    float* out = (float*)d_out;

    const int n = in_sizes[0] / 2;  // x is [N,2]
    const int E = in_sizes[1] / 2;  // edge_index is [2,E]
    const int* src = ei;
    const int* dst = ei + E;

    const int P  = (n + PART - 1) >> LPBIT;  // 98
    const int B1 = (E + EPB - 1) / EPB;      // 782

    int* ws = (int*)d_ws;
    int* colTotal = ws;                                      // 1024
    int* colStart = ws + 1024;                               // 1024
    int* cntmatA  = ws + 2048;                               // B1*P
    size_t cmsz = (((size_t)B1 * P) + 3) & ~(size_t)3;
    int* runStart = cntmatA + cmsz;                          // P*BC*RSTR
    size_t rssz = (((size_t)P * BC * RSTR) + 3) & ~(size_t)3;
    unsigned* packed = (unsigned*)(runStart + rssz);         // E
    int* srcsorted = (int*)(packed + E);                     // E
    // packed region dead after localC; overlay node buffers + partials.
    // partial1 (dead after combine1) and partial2 share one region.
    size_t nd = (size_t)P << LPBIT;                          // 200704
    float* dinv = (float*)packed;                            // nd
    float* g    = dinv + nd;                                 // 2*nd
    float* hs2  = g + 2 * nd;                                // 4*nd
    float* partial = hs2 + 4 * nd;   // max(3136,6272)*512 = 3.21M words
    // 7*nd + 3.21M = 4.62M <= E = 6.4M  ✓ (22% margin)

    const int gN  = (n + 511) / 512;
    const int gA1 = P * BC * (PART / NSL1);   // 3136
    const int gA2 = P * BC * (PART / NSL2);   // 6272

    countA_kernel    <<<B1, 512, 0, stream>>>(dst, cntmatA, E, P);
    colscanA_kernel  <<<P, 256, 0, stream>>>(cntmatA, colTotal, B1, P);
    totalscanA_kernel<<<1, 256, 0, stream>>>(colTotal, colStart, P, E);
    scatterA_kernel  <<<B1, 512, 0, stream>>>(src, dst, cntmatA, colStart, packed, E, P);
    localC_kernel    <<<P * BC, 512, 0, stream>>>(packed, colStart, runStart, srcsorted);
    dinvg_kernel     <<<gN, 512, 0, stream>>>(runStart, x, dinv, g, n);
    agg1p_kernel     <<<gA1, 512, 0, stream>>>(srcsorted, runStart, g, partial);
    combine1_kernel  <<<gN, 512, 0, stream>>>(partial, g, dinv, W1, b1, W2, hs2, n);
    agg2p_kernel     <<<gA2, 512, 0, stream>>>(srcsorted, runStart, hs2, partial);
    combine2_kernel  <<<gN, 512, 0, stream>>>(partial, hs2, dinv, b2, out, n);
}

// Round 11
// 235.014 us; speedup vs baseline: 4.3254x; 1.0406x over previous
//
#include <hip/hip_runtime.h>

// GCN 2-layer on MI355X — Round 21: R20 sort pipeline (verified) + agg
// consolidation: block = node-slice ACROSS all 4 buckets, 4 sequential
// stage+sum phase-pairs with REGISTER accumulation -> no partial buffers,
// no combine kernels. agg1 784 blocks / agg2 1568 blocks (3-6/CU, 19-39KB
// LDS, 3-4 resident/CU -> cross-block phase overlap). agg2 thread=(node,
// comp) writes out[4i+c] directly (coalesced).
//
// Budget model (R20 counters): fill 44 (harness poison, fixed) +
// scatterA 45 + countA ~40 + localC ~40 (each ~= LDS-atomic pipe tax,
// measured R15/R17/R18: no lowering escapes it) + scans/dinvg ~11 +
// aggs ~55 -> this round targets aggs' partial round-trip (~15us).
//
// g[j] = x[j]*dinv[j].  layer1: hs2 via relu(dinv*(sum g)+b1)@W2*dinv
// layer2: out[i] = dinv[i]*(sum hs2[src]+hs2[i]) + b2

#define EPB   8192   // edges per pass-A block
#define PART  2048   // nodes per partition
#define LPBIT 11
#define SRCB  18     // src bits in packed
#define BC    4      // localC sub-blocks per dp
#define RSTR  2049   // runStart stride per (dp,b)
#define STCAP 17408  // LDS stage words (68 KB); max expected ~16.6k
#define NSL1  256    // nodes per agg1 slice (8 slices per dp)
#define CAP1  2304   // agg1 staged edges per bucket-phase (mean ~2064, +5σ)
#define NSL2  128    // nodes per agg2 slice (16 slices per dp)
#define CAP2  1280   // agg2 staged edges per bucket-phase (mean ~1032, +7σ)

// ---------------- Pass A ----------------

__global__ __launch_bounds__(512) void countA_kernel(
    const int* __restrict__ dst, int* __restrict__ cntmat, int E, int P) {
    __shared__ int cnt[128];
    int tid = threadIdx.x;
    if (tid < 128) cnt[tid] = 0;
    __syncthreads();
    int nv4 = E >> 2;
    int b4 = (blockIdx.x * EPB) >> 2;
    int e4 = min(b4 + (EPB >> 2), nv4);
    const int4* d4 = (const int4*)dst;
    #pragma unroll
    for (int k = 0; k < (EPB >> 2); k += 512) {
        int i = b4 + k + tid;
        if (i < e4) {
            int4 d = d4[i];
            atomicAdd(&cnt[d.x >> LPBIT], 1);
            atomicAdd(&cnt[d.y >> LPBIT], 1);
            atomicAdd(&cnt[d.z >> LPBIT], 1);
            atomicAdd(&cnt[d.w >> LPBIT], 1);
        }
    }
    if (blockIdx.x == gridDim.x - 1) {  // scalar tail (E % 4)
        int e = (nv4 << 2) + tid;
        if (e < E) atomicAdd(&cnt[dst[e] >> LPBIT], 1);
    }
    __syncthreads();
    int* row = cntmat + (size_t)blockIdx.x * P;
    if (tid < P) row[tid] = cnt[tid];
}

__global__ __launch_bounds__(256) void colscanA_kernel(
    int* __restrict__ cntmat, int* __restrict__ colTotal, int B, int P) {
    __shared__ int sdata[256];
    int p = blockIdx.x, tid = threadIdx.x;
    int v[4];
    int s = 0;
    #pragma unroll
    for (int k = 0; k < 4; k++) {
        int b = tid * 4 + k;
        v[k] = (b < B) ? cntmat[(size_t)b * P + p] : 0;
        s += v[k];
    }
    int x = s;
    sdata[tid] = x;
    __syncthreads();
    for (int off = 1; off < 256; off <<= 1) {
        int t = (tid >= off) ? sdata[tid - off] : 0;
        __syncthreads();
        x += t;
        sdata[tid] = x;
        __syncthreads();
    }
    int run = x - s;
    #pragma unroll
    for (int k = 0; k < 4; k++) {
        int b = tid * 4 + k;
        if (b < B) cntmat[(size_t)b * P + p] = run;
        run += v[k];
    }
    if (tid == 255) colTotal[p] = x;
}

__global__ __launch_bounds__(256) void totalscanA_kernel(
    const int* __restrict__ colTotal, int* __restrict__ colStart,
    int P, int E) {
    __shared__ int sdata[256];
    int tid = threadIdx.x;
    int v[4];
    int s = 0;
    #pragma unroll
    for (int k = 0; k < 4; k++) {
        int i = tid * 4 + k;
        v[k] = (i < P) ? colTotal[i] : 0;
        s += v[k];
    }
    int x = s;
    sdata[tid] = x;
    __syncthreads();
    for (int off = 1; off < 256; off <<= 1) {
        int t = (tid >= off) ? sdata[tid - off] : 0;
        __syncthreads();
        x += t;
        sdata[tid] = x;
        __syncthreads();
    }
    int run = x - s;
    #pragma unroll
    for (int k = 0; k < 4; k++) {
        int i = tid * 4 + k;
        if (i < P) colStart[i] = run;
        run += v[k];
    }
    if (tid == 0) colStart[P] = E;
}

__global__ __launch_bounds__(512) void scatterA_kernel(
    const int* __restrict__ src, const int* __restrict__ dst,
    const int* __restrict__ cntmat, const int* __restrict__ colStart,
    unsigned* __restrict__ packed, int E, int P) {
    __shared__ int cur[128];
    int tid = threadIdx.x;
    if (tid < P) cur[tid] = colStart[tid] + cntmat[(size_t)blockIdx.x * P + tid];
    __syncthreads();
    int nv4 = E >> 2;
    int b4 = (blockIdx.x * EPB) >> 2;
    int e4 = min(b4 + (EPB >> 2), nv4);
    const int4* d4 = (const int4*)dst;
    const int4* s4 = (const int4*)src;
    #pragma unroll
    for (int k = 0; k < (EPB >> 2); k += 512) {
        int i = b4 + k + tid;
        if (i < e4) {
            int4 d = d4[i];
            int4 sv = s4[i];
            int p0 = atomicAdd(&cur[d.x >> LPBIT], 1);
            packed[p0] = ((unsigned)(d.x & (PART - 1)) << SRCB) | (unsigned)sv.x;
            int p1 = atomicAdd(&cur[d.y >> LPBIT], 1);
            packed[p1] = ((unsigned)(d.y & (PART - 1)) << SRCB) | (unsigned)sv.y;
            int p2 = atomicAdd(&cur[d.z >> LPBIT], 1);
            packed[p2] = ((unsigned)(d.z & (PART - 1)) << SRCB) | (unsigned)sv.z;
            int p3 = atomicAdd(&cur[d.w >> LPBIT], 1);
            packed[p3] = ((unsigned)(d.w & (PART - 1)) << SRCB) | (unsigned)sv.w;
        }
    }
    if (blockIdx.x == gridDim.x - 1) {  // scalar tail
        int e = (nv4 << 2) + tid;
        if (e < E) {
            int d = dst[e];
            int pos = atomicAdd(&cur[d >> LPBIT], 1);
            packed[pos] = ((unsigned)(d & (PART - 1)) << SRCB) | (unsigned)src[e];
        }
    }
}

// ---------------- localC: in-place LDS counting sort per 16k range --------

__global__ __launch_bounds__(512) void localC_kernel(
    const unsigned* __restrict__ packed, const int* __restrict__ colStart,
    int* __restrict__ runStart, int* __restrict__ srcsorted) {
    __shared__ int hist[PART];      // counts -> absolute cursors
    __shared__ int sdata[512];
    __shared__ unsigned stage[STCAP];
    int tid = threadIdx.x;
    int dp = blockIdx.x >> 2, b = blockIdx.x & (BC - 1);
    int s0 = colStart[dp], len = colStart[dp + 1] - s0;
    int lo = s0 + (int)(((long long)len * b) / BC);
    int hi = s0 + (int)(((long long)len * (b + 1)) / BC);
    for (int k = tid; k < PART; k += 512) hist[k] = 0;
    __syncthreads();
    for (int i = lo + tid; i < hi; i += 512)
        atomicAdd(&hist[packed[i] >> SRCB], 1);
    __syncthreads();
    // exclusive scan of hist[2048], 4 elems/thread
    int off = tid * 4;
    int v0 = hist[off], v1 = hist[off + 1], v2 = hist[off + 2], v3 = hist[off + 3];
    int s = v0 + v1 + v2 + v3;
    int x = s;
    sdata[tid] = x;
    __syncthreads();
    for (int o = 1; o < 512; o <<= 1) {
        int t = (tid >= o) ? sdata[tid - o] : 0;
        __syncthreads();
        x += t;
        sdata[tid] = x;
        __syncthreads();
    }
    int run = x - s;  // exclusive prefix of this thread's 4 buckets
    int* rs = runStart + (size_t)(dp * BC + b) * RSTR;
    int c0 = lo + run, c1 = c0 + v0, c2 = c1 + v1, c3 = c2 + v2;
    rs[off] = c0; rs[off + 1] = c1; rs[off + 2] = c2; rs[off + 3] = c3;
    __syncthreads();  // all v-reads done before cursor overwrite
    hist[off] = c0; hist[off + 1] = c1; hist[off + 2] = c2; hist[off + 3] = c3;
    if (tid == 0) rs[PART] = hi;  // end sentinel
    __syncthreads();
    // place into LDS stage (absolute pos - lo), then coalesced flush
    int total = hi - lo;
    bool ovf = total > STCAP;
    for (int i = lo + tid; i < hi; i += 512) {
        unsigned w = packed[i];
        int pos = atomicAdd(&hist[w >> SRCB], 1);
        unsigned sv = w & ((1u << SRCB) - 1);
        if (!ovf) stage[pos - lo] = sv;
        else srcsorted[pos] = (int)sv;
    }
    __syncthreads();
    if (!ovf)
        for (int j = tid; j < total; j += 512) srcsorted[lo + j] = (int)stage[j];
}

// ---------------- Node-side ----------------

__global__ __launch_bounds__(512) void dinvg_kernel(
    const int* __restrict__ runStart, const float* __restrict__ x,
    float* __restrict__ dinv, float* __restrict__ g, int n) {
    int i = blockIdx.x * 512 + threadIdx.x;
    if (i >= n) return;
    int dp = i >> LPBIT, ld = i & (PART - 1);
    int deg = 0;
    #pragma unroll
    for (int b = 0; b < BC; b++) {
        const int* rs = runStart + (size_t)(dp * BC + b) * RSTR + ld;
        deg += rs[1] - rs[0];
    }
    float d = rsqrtf((float)deg + 1.0f);  // +1 self-loop
    dinv[i] = d;
    float2 xv = ((const float2*)x)[i];
    ((float2*)g)[i] = make_float2(xv.x * d, xv.y * d);
}

// ---------------- Fused slice aggregation (all 4 buckets per block) ------
// Register accumulation across 4 stage+sum phases; no partials/combines.

__global__ __launch_bounds__(512) void agg1f_kernel(
    const int* __restrict__ srcsorted, const int* __restrict__ runStart,
    const float* __restrict__ g, const float* __restrict__ dinv,
    const float* __restrict__ W1, const float* __restrict__ b1,
    const float* __restrict__ W2, float* __restrict__ hs2, int n) {
    __shared__ float2 stage[CAP1];
    __shared__ int srs[NSL1 + 1];
    __shared__ float sres[NSL1][2];
    int tid = threadIdx.x;
    int dp = blockIdx.x >> 3, sl = blockIdx.x & 7;
    int nid = tid >> 1, c = tid & 1;       // 256 nodes x 2 comps
    const float2* gp = (const float2*)g;
    float acc = 0.0f;
    #pragma unroll
    for (int b = 0; b < BC; b++) {
        const int* rs = runStart + (size_t)(dp * BC + b) * RSTR + sl * NSL1;
        if (tid <= NSL1) srs[tid] = rs[tid];
        __syncthreads();
        int lo = srs[0], hi = srs[NSL1];
        bool ovf = (hi - lo) > CAP1;       // expected never (+5σ)
        if (!ovf)
            for (int e = lo + tid; e < hi; e += 512)
                stage[e - lo] = gp[srcsorted[e]];
        __syncthreads();
        int a = srs[nid] - lo, bnd = srs[nid + 1] - lo;
        if (!ovf) {
            const float* st = (const float*)stage;
            for (int j = a; j < bnd; j++) acc += st[j * 2 + c];
        } else {
            for (int j = a; j < bnd; j++)
                acc += g[2 * (size_t)srcsorted[lo + j] + c];
        }
        __syncthreads();                   // stage reuse next bucket
    }
    sres[nid][c] = acc;
    __syncthreads();
    if (tid < NSL1) {
        int i = ((dp << LPBIT) | (sl * NSL1)) + tid;
        if (i < n) {
            float d = dinv[i];
            float2 gi = gp[i];
            float s0 = (sres[tid][0] + gi.x) * d;
            float s1 = (sres[tid][1] + gi.y) * d;
            float oc0 = 0.0f, oc1 = 0.0f, oc2 = 0.0f, oc3 = 0.0f;
            #pragma unroll
            for (int f = 0; f < 8; f++) {
                float h = fmaxf(s0 * W1[f] + s1 * W1[8 + f] + b1[f], 0.0f);
                oc0 += h * W2[4 * f];
                oc1 += h * W2[4 * f + 1];
                oc2 += h * W2[4 * f + 2];
                oc3 += h * W2[4 * f + 3];
            }
            float4 o;
            o.x = oc0 * d; o.y = oc1 * d; o.z = oc2 * d; o.w = oc3 * d;
            ((float4*)hs2)[i] = o;
        }
    }
}

__global__ __launch_bounds__(512) void agg2f_kernel(
    const int* __restrict__ srcsorted, const int* __restrict__ runStart,
    const float* __restrict__ hs2, const float* __restrict__ dinv,
    const float* __restrict__ b2, float* __restrict__ out, int n) {
    __shared__ float4 stage[CAP2];
    __shared__ int srs[NSL2 + 1];
    int tid = threadIdx.x;
    int dp = blockIdx.x >> 4, sl = blockIdx.x & 15;
    int nid = tid >> 2, c = tid & 3;       // 128 nodes x 4 comps
    const float4* hp = (const float4*)hs2;
    float acc = 0.0f;
    #pragma unroll
    for (int b = 0; b < BC; b++) {
        const int* rs = runStart + (size_t)(dp * BC + b) * RSTR + sl * NSL2;
        if (tid <= NSL2) srs[tid] = rs[tid];
        __syncthreads();
        int lo = srs[0], hi = srs[NSL2];
        bool ovf = (hi - lo) > CAP2;       // expected never (+7σ)
        if (!ovf)
            for (int e = lo + tid; e < hi; e += 512)
                stage[e - lo] = hp[srcsorted[e]];
        __syncthreads();
        int a = srs[nid] - lo, bnd = srs[nid + 1] - lo;
        if (!ovf) {
            const float* st = (const float*)stage;
            for (int j = a; j < bnd; j++) acc += st[j * 4 + c];
        } else {
            for (int j = a; j < bnd; j++)
                acc += hs2[4 * (size_t)srcsorted[lo + j] + c];
        }
        __syncthreads();                   // stage reuse next bucket
    }
    int i = ((dp << LPBIT) | (sl * NSL2)) + nid;
    if (i < n) {
        float d = dinv[i];
        float hv = hs2[4 * (size_t)i + c];
        out[4 * (size_t)i + c] = d * (acc + hv) + b2[c];  // coalesced
    }
}

extern "C" void kernel_launch(void* const* d_in, const int* in_sizes, int n_in,
                              void* d_out, int out_size, void* d_ws, size_t ws_size,
                              hipStream_t stream) {
    const float* x   = (const float*)d_in[0];
    const int*   ei  = (const int*)d_in[1];
    const float* W1  = (const float*)d_in[2];
    const float* b1  = (const float*)d_in[3];
    const float* W2  = (const float*)d_in[4];
    const float* b2  = (const float*)d_in[5];
    float* out = (float*)d_out;

    const int n = in_sizes[0] / 2;  // x is [N,2]
    const int E = in_sizes[1] / 2;  // edge_index is [2,E]
    const int* src = ei;
    const int* dst = ei + E;

    const int P  = (n + PART - 1) >> LPBIT;  // 98
    const int B1 = (E + EPB - 1) / EPB;      // 782

    int* ws = (int*)d_ws;
    int* colTotal = ws;                                      // 1024
    int* colStart = ws + 1024;                               // 1024
    int* cntmatA  = ws + 2048;                               // B1*P
    size_t cmsz = (((size_t)B1 * P) + 3) & ~(size_t)3;
    int* runStart = cntmatA + cmsz;                          // P*BC*RSTR
    size_t rssz = (((size_t)P * BC * RSTR) + 3) & ~(size_t)3;
    unsigned* packed = (unsigned*)(runStart + rssz);         // E
    int* srcsorted = (int*)(packed + E);                     // E
    // packed region dead after localC; overlay node buffers (7*nd <= E):
    size_t nd = (size_t)P << LPBIT;                          // 200704
    float* dinv = (float*)packed;                            // nd
    float* g    = dinv + nd;                                 // 2*nd
    float* hs2  = g + 2 * nd;                                // 4*nd

    const int gN  = (n + 511) / 512;
    const int gA1 = P * (PART / NSL1);   // 784
    const int gA2 = P * (PART / NSL2);   // 1568

    countA_kernel    <<<B1, 512, 0, stream>>>(dst, cntmatA, E, P);
    colscanA_kernel  <<<P, 256, 0, stream>>>(cntmatA, colTotal, B1, P);
    totalscanA_kernel<<<1, 256, 0, stream>>>(colTotal, colStart, P, E);
    scatterA_kernel  <<<B1, 512, 0, stream>>>(src, dst, cntmatA, colStart, packed, E, P);
    localC_kernel    <<<P * BC, 512, 0, stream>>>(packed, colStart, runStart, srcsorted);
    dinvg_kernel     <<<gN, 512, 0, stream>>>(runStart, x, dinv, g, n);
    agg1f_kernel     <<<gA1, 512, 0, stream>>>(srcsorted, runStart, g, dinv, W1, b1, W2, hs2, n);
    agg2f_kernel     <<<gA2, 512, 0, stream>>>(srcsorted, runStart, hs2, dinv, b2, out, n);
}